// Round 3
// baseline (383.817 us; speedup 1.0000x reference)
//
#include <hip/hip_runtime.h>
#include <math.h>

#define TTOK 16384
#define DD   4096
#define EE   64
#define TM   32            // tokens per block
#define BK   64            // K per staged chunk
#define NCH  (DD / BK)     // 64 chunks
#define WCH  (EE * BK)     // shorts per W chunk buffer (4096 = 8 KB)

typedef __attribute__((ext_vector_type(8))) short short8;
typedef __attribute__((ext_vector_type(4))) float f32x4;

static __device__ __forceinline__ unsigned short f2bf(float f) {
    unsigned u = __float_as_uint(f);
    u += 0x7FFFu + ((u >> 16) & 1u);          // RTNE
    return (unsigned short)(u >> 16);
}
static __device__ __forceinline__ float bf2f(unsigned short h) {
    return __uint_as_float(((unsigned)h) << 16);
}
// 8 consecutive fp32 -> bf16 hi + bf16 lo (lo = rn(v - hi)); lo*lo dropped in GEMM
static __device__ __forceinline__ void cvt8(float4 a, float4 b, short8& hi, short8& lo) {
    const float v[8] = {a.x, a.y, a.z, a.w, b.x, b.y, b.z, b.w};
#pragma unroll
    for (int j = 0; j < 8; ++j) {
        const unsigned short h = f2bf(v[j]);
        hi[j] = (short)h;
        lo[j] = (short)f2bf(v[j] - bf2f(h));
    }
}

// 16B global -> LDS direct (no register round-trip). size must be literal 16.
static __device__ __forceinline__ void gload16(const unsigned short* g, unsigned short* l) {
    __builtin_amdgcn_global_load_lds(
        (const __attribute__((address_space(1))) unsigned int*)g,
        (__attribute__((address_space(3))) unsigned int*)l, 16, 0, 0);
}

// W -> bf16 hi/lo, stored PRE-SWIZZLED in chunk-major layout:
// chunk kc occupies granules [kc*512, kc*512+512); row r granule j lives at
// slot kc*512 + r*8 + (j ^ (r&7))  -- exactly the LDS image moe_fused wants,
// so global_load_lds with a linear LDS dest reproduces the swizzle (guide G21).
__global__ void w_convert(const float* __restrict__ W,
                          unsigned short* __restrict__ whi,
                          unsigned short* __restrict__ wlo) {
    const int t  = blockIdx.x * blockDim.x + threadIdx.x;  // 0..32767, 8 elems each
    const int r  = t >> 9;           // expert row (512 granules per row)
    const int g  = t & 511;
    const int kc = g >> 3;           // K-chunk
    const int j  = g & 7;            // 16B granule within chunk
    const float* src = W + (size_t)r * DD + kc * BK + j * 8;
    const float4 a = *reinterpret_cast<const float4*>(src);
    const float4 b = *reinterpret_cast<const float4*>(src + 4);
    short8 h, l;
    cvt8(a, b, h, l);
    const int slot = kc * 512 + r * 8 + (j ^ (r & 7));
    *reinterpret_cast<short8*>(whi + (size_t)slot * 8) = h;
    *reinterpret_cast<short8*>(wlo + (size_t)slot * 8) = l;
}

// One block = 32 tokens x 64 experts x K=4096, fused with gating.
// x: register prefetch + cvt8 + ds_write (needs fp32->bf16 conversion).
// W: global_load_lds direct into double-buffered LDS, issued 1 chunk ahead.
// Sync is structural: W(k+1) issued BEFORE x(k+1) (sched_barrier-pinned), so the
// compiler's in-order vmcnt wait on x(k) at cvt8 implies the older W(k) landed.
// Raw s_barrier + lgkmcnt(0) (NOT __syncthreads) so prefetches stay in flight.
__global__ __launch_bounds__(256, 2)
void moe_fused(const float* __restrict__ x,
               const unsigned short* __restrict__ whi,
               const unsigned short* __restrict__ wlo,
               float* __restrict__ out)
{
    __shared__ unsigned short xh[TM * 64];     // 4 KB bf16 x hi
    __shared__ unsigned short xl[TM * 64];     // 4 KB bf16 x lo
    __shared__ unsigned short whs[2 * WCH];    // 16 KB W hi, double-buffered
    __shared__ unsigned short wls[2 * WCH];    // 16 KB W lo, double-buffered
    __shared__ float lg[TM * 68];              // logits tile, padded stride

    const int tid  = threadIdx.x;
    const int wv   = tid >> 6;
    const int lane = tid & 63;
    const int m    = lane & 15;
    const int q    = lane >> 4;
    const int tg   = wv >> 1;                  // token group 0..1
    const int eh   = wv & 1;                   // expert half 0..1
    const int t0   = blockIdx.x * TM;

    // x staging: one row per thread, 16B granule sj, XOR-swizzled into xh/xl
    const int sr = tid >> 3;                   // 0..31
    const int sj = tid & 7;
    const int xo = sr * 64 + (sj ^ (sr & 7)) * 8;
    const float* gx = x + (size_t)(t0 + sr) * DD + sj * 8;

    // W staging slots (16B granules): this thread covers slots ws0 and ws1
    const int ws0 = wv * 64 + lane;            // 0..255
    const int ws1 = 256 + ws0;                 // 256..511

    f32x4 acc0 = (f32x4){0.f, 0.f, 0.f, 0.f};
    f32x4 acc1 = (f32x4){0.f, 0.f, 0.f, 0.f};

    // prologue: W(0) -> buf0 (issued before x(0): ordering is the sync invariant)
    gload16(whi + (size_t)ws0 * 8, whs + ws0 * 8);
    gload16(whi + (size_t)ws1 * 8, whs + ws1 * 8);
    gload16(wlo + (size_t)ws0 * 8, wls + ws0 * 8);
    gload16(wlo + (size_t)ws1 * 8, wls + ws1 * 8);
    __builtin_amdgcn_sched_barrier(0);
    float4 fx0 = *reinterpret_cast<const float4*>(gx);
    float4 fx1 = *reinterpret_cast<const float4*>(gx + 4);

    const int sa  = m & 7;
    const int ra  = (16 * tg + m) * 64;        // A row base (token)
    const int rb0 = (32 * eh + m) * 64;        // B row base, expert tile e=0
    const int rb1 = (32 * eh + 16 + m) * 64;   // expert tile e=1

    for (int kc = 0; kc < NCH; ++kc) {
        __builtin_amdgcn_s_barrier();          // B1: all waves done with chunk kc-1
        __builtin_amdgcn_sched_barrier(0);
        if (kc + 1 < NCH) {                    // W(kc+1) -> other buffer
            const int nb = ((kc + 1) & 1) * WCH;
            const unsigned short* gh = whi + (size_t)(kc + 1) * WCH;
            const unsigned short* gl = wlo + (size_t)(kc + 1) * WCH;
            gload16(gh + (size_t)ws0 * 8, whs + nb + ws0 * 8);
            gload16(gh + (size_t)ws1 * 8, whs + nb + ws1 * 8);
            gload16(gl + (size_t)ws0 * 8, wls + nb + ws0 * 8);
            gload16(gl + (size_t)ws1 * 8, wls + nb + ws1 * 8);
        }
        __builtin_amdgcn_sched_barrier(0);     // pin: W-issue precedes everything below

        {   // stage x(kc): compiler's vmcnt wait here also retires the older W(kc)
            short8 h, l;
            cvt8(fx0, fx1, h, l);
            *reinterpret_cast<short8*>(xh + xo) = h;
            *reinterpret_cast<short8*>(xl + xo) = l;
        }
        if (kc + 1 < NCH) {                    // x(kc+1) register prefetch
            const int off = (kc + 1) * BK;
            fx0 = *reinterpret_cast<const float4*>(gx + off);
            fx1 = *reinterpret_cast<const float4*>(gx + off + 4);
        }

        asm volatile("s_waitcnt lgkmcnt(0)" ::: "memory");  // ds_writes visible
        __builtin_amdgcn_s_barrier();          // B2: staged chunk kc ready
        __builtin_amdgcn_sched_barrier(0);

        // compute chunk kc
        const int cb = (kc & 1) * WCH;
#pragma unroll
        for (int kss = 0; kss < 2; ++kss) {
            const int ca = ((4 * kss + q) ^ sa) * 8;
            const short8 ah  = *reinterpret_cast<const short8*>(xh + ra + ca);
            const short8 al  = *reinterpret_cast<const short8*>(xl + ra + ca);
            const short8 bh0 = *reinterpret_cast<const short8*>(whs + cb + rb0 + ca);
            const short8 bl0 = *reinterpret_cast<const short8*>(wls + cb + rb0 + ca);
            const short8 bh1 = *reinterpret_cast<const short8*>(whs + cb + rb1 + ca);
            const short8 bl1 = *reinterpret_cast<const short8*>(wls + cb + rb1 + ca);
            acc0 = __builtin_amdgcn_mfma_f32_16x16x32_bf16(ah, bh0, acc0, 0, 0, 0);
            acc0 = __builtin_amdgcn_mfma_f32_16x16x32_bf16(ah, bl0, acc0, 0, 0, 0);
            acc0 = __builtin_amdgcn_mfma_f32_16x16x32_bf16(al, bh0, acc0, 0, 0, 0);
            acc1 = __builtin_amdgcn_mfma_f32_16x16x32_bf16(ah, bh1, acc1, 0, 0, 0);
            acc1 = __builtin_amdgcn_mfma_f32_16x16x32_bf16(ah, bl1, acc1, 0, 0, 0);
            acc1 = __builtin_amdgcn_mfma_f32_16x16x32_bf16(al, bh1, acc1, 0, 0, 0);
        }
    }

    // accumulators -> LDS logits tile. D layout: row = 4q+i (token), col = m (expert)
    {
        float* lr = lg + (16 * tg + 4 * q) * 68 + 32 * eh + m;
#pragma unroll
        for (int i = 0; i < 4; ++i) {
            lr[i * 68]      = acc0[i];
            lr[i * 68 + 16] = acc1[i];
        }
    }
    __syncthreads();

    // gating: 8 threads per token, thread jj owns experts 8jj..8jj+7
    const int tt = tid >> 3;
    const int jj = tid & 7;
    const float* row = lg + tt * 68 + jj * 8;
    const float4 lv0 = *reinterpret_cast<const float4*>(row);
    const float4 lv1 = *reinterpret_cast<const float4*>(row + 4);
    const float r[8] = {lv0.x, lv0.y, lv0.z, lv0.w, lv1.x, lv1.y, lv1.z, lv1.w};

    // coalesced logits write
    float* gout = out + (size_t)(t0 + tt) * EE + jj * 8;
    *reinterpret_cast<float4*>(gout)     = lv0;
    *reinterpret_cast<float4*>(gout + 4) = lv1;

    // local top-2 (ascending expert order -> lowest index kept on ties)
    float v1 = -INFINITY, v2 = -INFINITY;
    int   i1 = 0, i2 = 0;
#pragma unroll
    for (int c = 0; c < 8; ++c) {
        const int e = jj * 8 + c;
        const float v = r[c];
        if (v > v1)      { v2 = v1; i2 = i1; v1 = v; i1 = e; }
        else if (v > v2) { v2 = v;  i2 = e; }
    }
    // butterfly merge across the 8-lane group (jax tie-break: lower index wins)
#pragma unroll
    for (int mk = 1; mk < 8; mk <<= 1) {
        const float ov1 = __shfl_xor(v1, mk);
        const int   oi1 = __shfl_xor(i1, mk);
        const float ov2 = __shfl_xor(v2, mk);
        const int   oi2 = __shfl_xor(i2, mk);
        const bool aw = (v1 > ov1) || (v1 == ov1 && i1 < oi1);
        const float c1v = aw ? v1 : ov1;  const int c1i = aw ? i1 : oi1;
        const float cav = aw ? v2 : ov2;  const int cai = aw ? i2 : oi2;
        const float cbv = aw ? ov1 : v1;  const int cbi = aw ? oi1 : i1;
        const bool bw = (cav > cbv) || (cav == cbv && cai < cbi);
        v1 = c1v; i1 = c1i;
        v2 = bw ? cav : cbv;
        i2 = bw ? cai : cbi;
    }

    // logsumexp over all 64 experts (v1 is the global max after the butterfly)
    float sm = 0.f;
#pragma unroll
    for (int c = 0; c < 8; ++c) sm += expf(r[c] - v1);
#pragma unroll
    for (int mk = 1; mk < 8; mk <<= 1) sm += __shfl_xor(sm, mk);

    const float logz = v1 + logf(sm);
    if (jj == 0) out[(size_t)2 * TTOK * EE + t0 + tt] = logz * logz;

    // 2-way softmax scores scattered into the 64-expert vector
    const float e21 = expf(v2 - v1);
    const float rr  = 1.f / (1.f + e21);
    const float sc1 = rr, sc2 = e21 * rr;
    float* sc = out + (size_t)TTOK * EE + (size_t)(t0 + tt) * EE + jj * 8;
    float vv[8];
#pragma unroll
    for (int c = 0; c < 8; ++c) {
        const int e = jj * 8 + c;
        vv[c] = (e == i1) ? sc1 : ((e == i2) ? sc2 : 0.f);
    }
    *reinterpret_cast<float4*>(sc)     = make_float4(vv[0], vv[1], vv[2], vv[3]);
    *reinterpret_cast<float4*>(sc + 4) = make_float4(vv[4], vv[5], vv[6], vv[7]);
}

extern "C" void kernel_launch(void* const* d_in, const int* in_sizes, int n_in,
                              void* d_out, int out_size, void* d_ws, size_t ws_size,
                              hipStream_t stream) {
    const float* x = (const float*)d_in[0];
    const float* W = (const float*)d_in[1];
    float* out = (float*)d_out;
    unsigned short* whi = (unsigned short*)d_ws;
    unsigned short* wlo = whi + (size_t)EE * DD;

    w_convert<<<dim3(EE * DD / 8 / 256), dim3(256), 0, stream>>>(W, whi, wlo);
    moe_fused<<<dim3(TTOK / TM), dim3(256), 0, stream>>>(x, whi, wlo, out);
}

// Round 5
// 377.768 us; speedup vs baseline: 1.0160x; 1.0160x over previous
//
#include <hip/hip_runtime.h>
#include <math.h>

#define TTOK 16384
#define DD   4096
#define EE   64
#define TM   32            // tokens per block
#define BK   64            // K per staged chunk
#define NCH  (DD / BK)     // 64 chunks

typedef __attribute__((ext_vector_type(8))) short short8;
typedef __attribute__((ext_vector_type(4))) float f32x4;

static __device__ __forceinline__ unsigned short f2bf(float f) {
    unsigned u = __float_as_uint(f);
    u += 0x7FFFu + ((u >> 16) & 1u);          // RTNE
    return (unsigned short)(u >> 16);
}
static __device__ __forceinline__ float bf2f(unsigned short h) {
    return __uint_as_float(((unsigned)h) << 16);
}
// 8 consecutive fp32 -> bf16 hi + bf16 lo (lo = rn(v - hi)); lo*lo dropped in GEMM
static __device__ __forceinline__ void cvt8(f32x4 a, f32x4 b, short8& hi, short8& lo) {
    const float v[8] = {a[0], a[1], a[2], a[3], b[0], b[1], b[2], b[3]};
#pragma unroll
    for (int j = 0; j < 8; ++j) {
        const unsigned short h = f2bf(v[j]);
        hi[j] = (short)h;
        lo[j] = (short)f2bf(v[j] - bf2f(h));
    }
}

// W -> bf16 hi/lo in FRAGMENT-MAJOR order: granule index
//   t = kc*512 + kss*256 + eg*64 + (q*16 + m)      (8 shorts per granule)
// holds W[eg*16+m][kc*64+kss*32+q*8 .. +8]. A wave loading granules
// [base + lane] with lane = q*16+m gets exactly the B fragment the MFMA wants
// (byte-identical to the old LDS-staged fragments) via one global_load_dwordx4.
__global__ void w_convert(const float* __restrict__ W,
                          unsigned short* __restrict__ whi,
                          unsigned short* __restrict__ wlo) {
    const int t   = blockIdx.x * blockDim.x + threadIdx.x;  // 0..32767
    const int m   = t & 15;
    const int q   = (t >> 4) & 3;
    const int eg  = (t >> 6) & 3;
    const int kss = (t >> 8) & 1;
    const int kc  = t >> 9;
    const int E   = eg * 16 + m;
    const int k0  = kc * BK + kss * 32 + q * 8;
    const float* src = W + (size_t)E * DD + k0;
    const f32x4 a = *reinterpret_cast<const f32x4*>(src);
    const f32x4 b = *reinterpret_cast<const f32x4*>(src + 4);
    short8 h, l;
    cvt8(a, b, h, l);
    *reinterpret_cast<short8*>(whi + (size_t)t * 8) = h;   // linear coalesced writes
    *reinterpret_cast<short8*>(wlo + (size_t)t * 8) = l;
}

// One block = 32 tokens x 64 experts x K=4096, fused with gating.
// x: LDS-staged (needs fp32->bf16 cvt + tg-reuse), register-prefetch DEPTH 2,
//    nontemporal loads (keep L2 for W).
// W: NO LDS -- B fragments loaded straight from L2-resident fragment-major
//    buffers into registers, prefetched 1 chunk ahead.
// vmem issue order per chunk: B(k+1) BEFORE x(k+2), so the in-order vmcnt wait
// on B regs at compute(k+1) never drags the younger x loads.
__global__ __launch_bounds__(256, 2)
void moe_fused(const float* __restrict__ x,
               const unsigned short* __restrict__ whi,
               const unsigned short* __restrict__ wlo,
               float* __restrict__ out)
{
    __shared__ unsigned short xh[TM * 64];     // 4 KB bf16 x hi
    __shared__ unsigned short xl[TM * 64];     // 4 KB bf16 x lo
    __shared__ float lg[TM * 68];              // logits tile, padded stride

    const int tid  = threadIdx.x;
    const int wv   = tid >> 6;
    const int lane = tid & 63;
    const int m    = lane & 15;
    const int q    = lane >> 4;
    const int tg   = wv >> 1;                  // token group 0..1
    const int eh   = wv & 1;                   // expert half 0..1
    const int t0   = blockIdx.x * TM;

    // x staging: one row per thread, 16B granule sj, XOR-swizzled into xh/xl
    const int sr = tid >> 3;                   // 0..31
    const int sj = tid & 7;
    const int xo = sr * 64 + (sj ^ (sr & 7)) * 8;
    const float* gx = x + (size_t)(t0 + sr) * DD + sj * 8;

    // B fragment base (shorts): chunk kc, kss, tile e -> kc*4096 + kss*2048 + (2eh+e)*512 + lane*8
    const int wb = eh * 1024 + lane * 8;

    f32x4 acc0 = (f32x4){0.f, 0.f, 0.f, 0.f};
    f32x4 acc1 = (f32x4){0.f, 0.f, 0.f, 0.f};

    // B regs: [kss][tile] hi/lo
    short8 pA0, pA1, pA2, pA3, pA4, pA5, pA6, pA7;   // chunk parity 0
    short8 pB0, pB1, pB2, pB3, pB4, pB5, pB6, pB7;   // chunk parity 1

    // prologue: B(0) -> pA, then x(0)/x(1) -> fxA/fxB (B first: see vmcnt note)
    {
        const unsigned short* bh = whi + wb;
        const unsigned short* bl = wlo + wb;
        pA0 = *reinterpret_cast<const short8*>(bh);
        pA1 = *reinterpret_cast<const short8*>(bh + 512);
        pA2 = *reinterpret_cast<const short8*>(bh + 2048);
        pA3 = *reinterpret_cast<const short8*>(bh + 2560);
        pA4 = *reinterpret_cast<const short8*>(bl);
        pA5 = *reinterpret_cast<const short8*>(bl + 512);
        pA6 = *reinterpret_cast<const short8*>(bl + 2048);
        pA7 = *reinterpret_cast<const short8*>(bl + 2560);
    }
    f32x4 fxA0 = __builtin_nontemporal_load(reinterpret_cast<const f32x4*>(gx));
    f32x4 fxA1 = __builtin_nontemporal_load(reinterpret_cast<const f32x4*>(gx + 4));
    f32x4 fxB0 = __builtin_nontemporal_load(reinterpret_cast<const f32x4*>(gx + BK));
    f32x4 fxB1 = __builtin_nontemporal_load(reinterpret_cast<const f32x4*>(gx + BK + 4));

    const int sa = m & 7;
    const int ra = (16 * tg + m) * 64;         // A row base (token)

#define CHUNK_BODY(KC, FX0, FX1, PC0, PC1, PC2, PC3, PC4, PC5, PC6, PC7,            \
                         PN0, PN1, PN2, PN3, PN4, PN5, PN6, PN7)                    \
    do {                                                                            \
        __builtin_amdgcn_s_barrier();          /* B1: prev chunk's A reads done */  \
        __builtin_amdgcn_sched_barrier(0);                                          \
        {   /* issue B(KC+1) -> next regs (before x issue!) */                      \
            const int kn_ = ((KC) + 1 < NCH) ? (KC) + 1 : NCH - 1;                  \
            const unsigned short* bh_ = whi + (size_t)kn_ * 4096 + wb;              \
            const unsigned short* bl_ = wlo + (size_t)kn_ * 4096 + wb;              \
            PN0 = *reinterpret_cast<const short8*>(bh_);                            \
            PN1 = *reinterpret_cast<const short8*>(bh_ + 512);                      \
            PN2 = *reinterpret_cast<const short8*>(bh_ + 2048);                     \
            PN3 = *reinterpret_cast<const short8*>(bh_ + 2560);                     \
            PN4 = *reinterpret_cast<const short8*>(bl_);                            \
            PN5 = *reinterpret_cast<const short8*>(bl_ + 512);                      \
            PN6 = *reinterpret_cast<const short8*>(bl_ + 2048);                     \
            PN7 = *reinterpret_cast<const short8*>(bl_ + 2560);                     \
        }                                                                           \
        __builtin_amdgcn_sched_barrier(0);                                          \
        {   /* stage x(KC) (vmcnt wait on FX regs happens here) */                  \
            short8 h_, l_;                                                          \
            cvt8(FX0, FX1, h_, l_);                                                 \
            *reinterpret_cast<short8*>(xh + xo) = h_;                               \
            *reinterpret_cast<short8*>(xl + xo) = l_;                               \
        }                                                                           \
        {   /* issue x(KC+2) -> same fx set (nontemporal) */                        \
            const int kf_ = ((KC) + 2 < NCH) ? (KC) + 2 : NCH - 1;                  \
            FX0 = __builtin_nontemporal_load(                                       \
                      reinterpret_cast<const f32x4*>(gx + kf_ * BK));               \
            FX1 = __builtin_nontemporal_load(                                       \
                      reinterpret_cast<const f32x4*>(gx + kf_ * BK + 4));           \
        }                                                                           \
        asm volatile("s_waitcnt lgkmcnt(0)" ::: "memory");  /* ds_writes visible */ \
        __builtin_amdgcn_s_barrier();          /* B2: staged chunk ready */         \
        __builtin_amdgcn_sched_barrier(0);                                          \
        {   /* compute chunk KC: A from LDS, B from regs */                         \
            const int ca0 = (q ^ sa) * 8;                                           \
            const int ca1 = ((4 + q) ^ sa) * 8;                                     \
            const short8 ah0 = *reinterpret_cast<const short8*>(xh + ra + ca0);     \
            const short8 al0 = *reinterpret_cast<const short8*>(xl + ra + ca0);     \
            const short8 ah1 = *reinterpret_cast<const short8*>(xh + ra + ca1);     \
            const short8 al1 = *reinterpret_cast<const short8*>(xl + ra + ca1);     \
            acc0 = __builtin_amdgcn_mfma_f32_16x16x32_bf16(ah0, PC0, acc0, 0, 0, 0);\
            acc0 = __builtin_amdgcn_mfma_f32_16x16x32_bf16(ah0, PC4, acc0, 0, 0, 0);\
            acc0 = __builtin_amdgcn_mfma_f32_16x16x32_bf16(al0, PC0, acc0, 0, 0, 0);\
            acc1 = __builtin_amdgcn_mfma_f32_16x16x32_bf16(ah0, PC1, acc1, 0, 0, 0);\
            acc1 = __builtin_amdgcn_mfma_f32_16x16x32_bf16(ah0, PC5, acc1, 0, 0, 0);\
            acc1 = __builtin_amdgcn_mfma_f32_16x16x32_bf16(al0, PC1, acc1, 0, 0, 0);\
            acc0 = __builtin_amdgcn_mfma_f32_16x16x32_bf16(ah1, PC2, acc0, 0, 0, 0);\
            acc0 = __builtin_amdgcn_mfma_f32_16x16x32_bf16(ah1, PC6, acc0, 0, 0, 0);\
            acc0 = __builtin_amdgcn_mfma_f32_16x16x32_bf16(al1, PC2, acc0, 0, 0, 0);\
            acc1 = __builtin_amdgcn_mfma_f32_16x16x32_bf16(ah1, PC3, acc1, 0, 0, 0);\
            acc1 = __builtin_amdgcn_mfma_f32_16x16x32_bf16(ah1, PC7, acc1, 0, 0, 0);\
            acc1 = __builtin_amdgcn_mfma_f32_16x16x32_bf16(al1, PC3, acc1, 0, 0, 0);\
        }                                                                           \
    } while (0)

    for (int kt = 0; kt < NCH / 2; ++kt) {
        const int k0 = 2 * kt;
        CHUNK_BODY(k0,     fxA0, fxA1, pA0, pA1, pA2, pA3, pA4, pA5, pA6, pA7,
                                       pB0, pB1, pB2, pB3, pB4, pB5, pB6, pB7);
        CHUNK_BODY(k0 + 1, fxB0, fxB1, pB0, pB1, pB2, pB3, pB4, pB5, pB6, pB7,
                                       pA0, pA1, pA2, pA3, pA4, pA5, pA6, pA7);
    }
#undef CHUNK_BODY

    // accumulators -> LDS logits tile. D layout: row = 4q+i (token), col = m (expert)
    {
        float* lr = lg + (16 * tg + 4 * q) * 68 + 32 * eh + m;
#pragma unroll
        for (int i = 0; i < 4; ++i) {
            lr[i * 68]      = acc0[i];
            lr[i * 68 + 16] = acc1[i];
        }
    }
    __syncthreads();

    // gating: 8 threads per token, thread jj owns experts 8jj..8jj+7
    const int tt = tid >> 3;
    const int jj = tid & 7;
    const float* row = lg + tt * 68 + jj * 8;
    const f32x4 lv0 = *reinterpret_cast<const f32x4*>(row);
    const f32x4 lv1 = *reinterpret_cast<const f32x4*>(row + 4);
    const float r[8] = {lv0[0], lv0[1], lv0[2], lv0[3], lv1[0], lv1[1], lv1[2], lv1[3]};

    // coalesced logits write
    float* gout = out + (size_t)(t0 + tt) * EE + jj * 8;
    *reinterpret_cast<f32x4*>(gout)     = lv0;
    *reinterpret_cast<f32x4*>(gout + 4) = lv1;

    // local top-2 (ascending expert order -> lowest index kept on ties)
    float v1 = -INFINITY, v2 = -INFINITY;
    int   i1 = 0, i2 = 0;
#pragma unroll
    for (int c = 0; c < 8; ++c) {
        const int e = jj * 8 + c;
        const float v = r[c];
        if (v > v1)      { v2 = v1; i2 = i1; v1 = v; i1 = e; }
        else if (v > v2) { v2 = v;  i2 = e; }
    }
    // butterfly merge across the 8-lane group (jax tie-break: lower index wins)
#pragma unroll
    for (int mk = 1; mk < 8; mk <<= 1) {
        const float ov1 = __shfl_xor(v1, mk);
        const int   oi1 = __shfl_xor(i1, mk);
        const float ov2 = __shfl_xor(v2, mk);
        const int   oi2 = __shfl_xor(i2, mk);
        const bool aw = (v1 > ov1) || (v1 == ov1 && i1 < oi1);
        const float c1v = aw ? v1 : ov1;  const int c1i = aw ? i1 : oi1;
        const float cav = aw ? v2 : ov2;  const int cai = aw ? i2 : oi2;
        const float cbv = aw ? ov1 : v1;  const int cbi = aw ? oi1 : i1;
        const bool bw = (cav > cbv) || (cav == cbv && cai < cbi);
        v1 = c1v; i1 = c1i;
        v2 = bw ? cav : cbv;
        i2 = bw ? cai : cbi;
    }

    // logsumexp over all 64 experts (v1 is the global max after the butterfly)
    float sm = 0.f;
#pragma unroll
    for (int c = 0; c < 8; ++c) sm += expf(r[c] - v1);
#pragma unroll
    for (int mk = 1; mk < 8; mk <<= 1) sm += __shfl_xor(sm, mk);

    const float logz = v1 + logf(sm);
    if (jj == 0) out[(size_t)2 * TTOK * EE + t0 + tt] = logz * logz;

    // 2-way softmax scores scattered into the 64-expert vector
    const float e21 = expf(v2 - v1);
    const float rr  = 1.f / (1.f + e21);
    const float sc1 = rr, sc2 = e21 * rr;
    float* sc = out + (size_t)TTOK * EE + (size_t)(t0 + tt) * EE + jj * 8;
    float vv[8];
#pragma unroll
    for (int c = 0; c < 8; ++c) {
        const int e = jj * 8 + c;
        vv[c] = (e == i1) ? sc1 : ((e == i2) ? sc2 : 0.f);
    }
    *reinterpret_cast<f32x4*>(sc)     = (f32x4){vv[0], vv[1], vv[2], vv[3]};
    *reinterpret_cast<f32x4*>(sc + 4) = (f32x4){vv[4], vv[5], vv[6], vv[7]};
}

extern "C" void kernel_launch(void* const* d_in, const int* in_sizes, int n_in,
                              void* d_out, int out_size, void* d_ws, size_t ws_size,
                              hipStream_t stream) {
    const float* x = (const float*)d_in[0];
    const float* W = (const float*)d_in[1];
    float* out = (float*)d_out;
    unsigned short* whi = (unsigned short*)d_ws;
    unsigned short* wlo = whi + (size_t)EE * DD;

    w_convert<<<dim3(EE * DD / 8 / 256), dim3(256), 0, stream>>>(W, whi, wlo);
    moe_fused<<<dim3(TTOK / TM), dim3(256), 0, stream>>>(x, whi, wlo, out);
}

// Round 6
// 377.226 us; speedup vs baseline: 1.0175x; 1.0014x over previous
//
#include <hip/hip_runtime.h>
#include <math.h>

#define TTOK 16384
#define DD   4096
#define EE   64
#define TM   32            // tokens per block
#define BK   64            // K per staged chunk
#define NCH  (DD / BK)     // 64 chunks

typedef __attribute__((ext_vector_type(8))) short short8;
typedef __attribute__((ext_vector_type(4))) float f32x4;

static __device__ __forceinline__ unsigned short f2bf(float f) {
    unsigned u = __float_as_uint(f);
    u += 0x7FFFu + ((u >> 16) & 1u);          // RTNE
    return (unsigned short)(u >> 16);
}
static __device__ __forceinline__ float bf2f(unsigned short h) {
    return __uint_as_float(((unsigned)h) << 16);
}
// 8 consecutive fp32 -> bf16 hi + bf16 lo (lo = rn(v - hi)); lo*lo dropped in GEMM
static __device__ __forceinline__ void cvt8(f32x4 a, f32x4 b, short8& hi, short8& lo) {
    const float v[8] = {a[0], a[1], a[2], a[3], b[0], b[1], b[2], b[3]};
#pragma unroll
    for (int j = 0; j < 8; ++j) {
        const unsigned short h = f2bf(v[j]);
        hi[j] = (short)h;
        lo[j] = (short)f2bf(v[j] - bf2f(h));
    }
}

// W -> bf16 hi/lo in FRAGMENT-MAJOR order: granule index
//   t = kc*512 + kss*256 + eg*64 + (q*16 + m)      (8 shorts per granule)
// holds W[eg*16+m][kc*64+kss*32+q*8 .. +8]. A wave loading granules
// [base + lane] with lane = q*16+m gets exactly the B fragment the MFMA wants.
__global__ void w_convert(const float* __restrict__ W,
                          unsigned short* __restrict__ whi,
                          unsigned short* __restrict__ wlo) {
    const int t   = blockIdx.x * blockDim.x + threadIdx.x;  // 0..32767
    const int m   = t & 15;
    const int q   = (t >> 4) & 3;
    const int eg  = (t >> 6) & 3;
    const int kss = (t >> 8) & 1;
    const int kc  = t >> 9;
    const int E   = eg * 16 + m;
    const int k0  = kc * BK + kss * 32 + q * 8;
    const float* src = W + (size_t)E * DD + k0;
    const f32x4 a = *reinterpret_cast<const f32x4*>(src);
    const f32x4 b = *reinterpret_cast<const f32x4*>(src + 4);
    short8 h, l;
    cvt8(a, b, h, l);
    *reinterpret_cast<short8*>(whi + (size_t)t * 8) = h;   // linear coalesced writes
    *reinterpret_cast<short8*>(wlo + (size_t)t * 8) = l;
}

// One block = 32 tokens x 64 experts x K=4096, fused with gating.
// x: LDS DOUBLE-buffered (fp32->bf16 cvt + tg-reuse), register prefetch depth 2,
//    nontemporal loads (keep L2 for W). ONE barrier per chunk (T3 minimum):
//    stage x(k+1)->buf[(k+1)&1] while computing k from buf[k&1]; barrier at end.
//    A wave reaching the barrier has consumed its ds_reads (MFMA issue forces
//    the lgkm wait), so one barrier per swap is sufficient.
// W: no LDS -- B fragments straight from L2-resident fragment-major buffers
//    into registers, prefetched 1 chunk ahead.
// vmcnt in-order invariant: every wait targets a load OLDER than all live
// prefetches (x(k+1) issued at k-2; B(k) issued at k-1 before x(k+2)), so no
// wait drains a younger prefetch.
__global__ __launch_bounds__(256, 2)
void moe_fused(const float* __restrict__ x,
               const unsigned short* __restrict__ whi,
               const unsigned short* __restrict__ wlo,
               float* __restrict__ out)
{
    __shared__ unsigned short xh[2][TM * 64];  // 2 x 4 KB bf16 x hi
    __shared__ unsigned short xl[2][TM * 64];  // 2 x 4 KB bf16 x lo
    __shared__ float lg[TM * 68];              // logits tile, padded stride

    const int tid  = threadIdx.x;
    const int wv   = tid >> 6;
    const int lane = tid & 63;
    const int m    = lane & 15;
    const int q    = lane >> 4;
    const int tg   = wv >> 1;                  // token group 0..1
    const int eh   = wv & 1;                   // expert half 0..1
    const int t0   = blockIdx.x * TM;

    // x staging: one row per thread, 16B granule sj, XOR-swizzled
    const int sr = tid >> 3;                   // 0..31
    const int sj = tid & 7;
    const int xo = sr * 64 + (sj ^ (sr & 7)) * 8;
    const float* gx = x + (size_t)(t0 + sr) * DD + sj * 8;

    // B fragment base (shorts): chunk kc, kss, tile e -> kc*4096 + kss*2048 + (2eh+e)*512 + lane*8
    const int wb = eh * 1024 + lane * 8;

    f32x4 acc0 = (f32x4){0.f, 0.f, 0.f, 0.f};
    f32x4 acc1 = (f32x4){0.f, 0.f, 0.f, 0.f};

    // B regs per chunk parity
    short8 pA0, pA1, pA2, pA3, pA4, pA5, pA6, pA7;   // even chunks
    short8 pB0, pB1, pB2, pB3, pB4, pB5, pB6, pB7;   // odd chunks

    // prologue: B(0) -> pA (issued first), then x regs, then stage x(0) -> buf0
    {
        const unsigned short* bh = whi + wb;
        const unsigned short* bl = wlo + wb;
        pA0 = *reinterpret_cast<const short8*>(bh);
        pA1 = *reinterpret_cast<const short8*>(bh + 512);
        pA2 = *reinterpret_cast<const short8*>(bh + 2048);
        pA3 = *reinterpret_cast<const short8*>(bh + 2560);
        pA4 = *reinterpret_cast<const short8*>(bl);
        pA5 = *reinterpret_cast<const short8*>(bl + 512);
        pA6 = *reinterpret_cast<const short8*>(bl + 2048);
        pA7 = *reinterpret_cast<const short8*>(bl + 2560);
    }
    // fxE holds even-indexed x chunks, fxO odd-indexed
    f32x4 fxE0 = __builtin_nontemporal_load(reinterpret_cast<const f32x4*>(gx));
    f32x4 fxE1 = __builtin_nontemporal_load(reinterpret_cast<const f32x4*>(gx + 4));
    f32x4 fxO0 = __builtin_nontemporal_load(reinterpret_cast<const f32x4*>(gx + BK));
    f32x4 fxO1 = __builtin_nontemporal_load(reinterpret_cast<const f32x4*>(gx + BK + 4));
    {   // stage x(0) -> buf0; refill fxE = x(2)
        short8 h0, l0;
        cvt8(fxE0, fxE1, h0, l0);
        *reinterpret_cast<short8*>(&xh[0][xo]) = h0;
        *reinterpret_cast<short8*>(&xl[0][xo]) = l0;
        fxE0 = __builtin_nontemporal_load(reinterpret_cast<const f32x4*>(gx + 2 * BK));
        fxE1 = __builtin_nontemporal_load(reinterpret_cast<const f32x4*>(gx + 2 * BK + 4));
    }
    asm volatile("s_waitcnt lgkmcnt(0)" ::: "memory");
    __builtin_amdgcn_s_barrier();              // buf0 visible

    const int sa = m & 7;
    const int ra = (16 * tg + m) * 64;         // A row base (token)

// chunk KC: issue B(KC+1)->PN*, stage x(KC+1) (regs FX*) -> buf WB, refill FX*
// with x(KC+3), compute KC from buf RB with PC*, one lgkmcnt+barrier.
#define CHUNK_BODY(KC, WB, RB, FX0, FX1, PC0, PC1, PC2, PC3, PC4, PC5, PC6, PC7,    \
                                 PN0, PN1, PN2, PN3, PN4, PN5, PN6, PN7)            \
    do {                                                                            \
        {   /* issue B(KC+1) (first: every later wait targets an older load) */     \
            const int kn_ = ((KC) + 1 < NCH) ? (KC) + 1 : NCH - 1;                  \
            const unsigned short* bh_ = whi + (size_t)kn_ * 4096 + wb;              \
            const unsigned short* bl_ = wlo + (size_t)kn_ * 4096 + wb;              \
            PN0 = *reinterpret_cast<const short8*>(bh_);                            \
            PN1 = *reinterpret_cast<const short8*>(bh_ + 512);                      \
            PN2 = *reinterpret_cast<const short8*>(bh_ + 2048);                     \
            PN3 = *reinterpret_cast<const short8*>(bh_ + 2560);                     \
            PN4 = *reinterpret_cast<const short8*>(bl_);                            \
            PN5 = *reinterpret_cast<const short8*>(bl_ + 512);                      \
            PN6 = *reinterpret_cast<const short8*>(bl_ + 2048);                     \
            PN7 = *reinterpret_cast<const short8*>(bl_ + 2560);                     \
        }                                                                           \
        __builtin_amdgcn_sched_barrier(0);                                          \
        {   /* stage x(KC+1) -> buf WB (vmcnt wait: x(KC+1) issued at KC-2) */      \
            short8 h_, l_;                                                          \
            cvt8(FX0, FX1, h_, l_);                                                 \
            *reinterpret_cast<short8*>(&xh[WB][xo]) = h_;                           \
            *reinterpret_cast<short8*>(&xl[WB][xo]) = l_;                           \
        }                                                                           \
        {   /* refill FX with x(KC+3) (nontemporal) */                              \
            const int kf_ = ((KC) + 3 < NCH) ? (KC) + 3 : NCH - 1;                  \
            FX0 = __builtin_nontemporal_load(                                       \
                      reinterpret_cast<const f32x4*>(gx + kf_ * BK));               \
            FX1 = __builtin_nontemporal_load(                                       \
                      reinterpret_cast<const f32x4*>(gx + kf_ * BK + 4));           \
        }                                                                           \
        {   /* compute chunk KC: A from buf RB, B from regs */                      \
            const int ca0 = (q ^ sa) * 8;                                           \
            const int ca1 = ((4 + q) ^ sa) * 8;                                     \
            const short8 ah0 = *reinterpret_cast<const short8*>(&xh[RB][ra + ca0]); \
            const short8 al0 = *reinterpret_cast<const short8*>(&xl[RB][ra + ca0]); \
            const short8 ah1 = *reinterpret_cast<const short8*>(&xh[RB][ra + ca1]); \
            const short8 al1 = *reinterpret_cast<const short8*>(&xl[RB][ra + ca1]); \
            acc0 = __builtin_amdgcn_mfma_f32_16x16x32_bf16(ah0, PC0, acc0, 0, 0, 0);\
            acc0 = __builtin_amdgcn_mfma_f32_16x16x32_bf16(ah0, PC4, acc0, 0, 0, 0);\
            acc0 = __builtin_amdgcn_mfma_f32_16x16x32_bf16(al0, PC0, acc0, 0, 0, 0);\
            acc1 = __builtin_amdgcn_mfma_f32_16x16x32_bf16(ah0, PC1, acc1, 0, 0, 0);\
            acc1 = __builtin_amdgcn_mfma_f32_16x16x32_bf16(ah0, PC5, acc1, 0, 0, 0);\
            acc1 = __builtin_amdgcn_mfma_f32_16x16x32_bf16(al0, PC1, acc1, 0, 0, 0);\
            acc0 = __builtin_amdgcn_mfma_f32_16x16x32_bf16(ah1, PC2, acc0, 0, 0, 0);\
            acc0 = __builtin_amdgcn_mfma_f32_16x16x32_bf16(ah1, PC6, acc0, 0, 0, 0);\
            acc0 = __builtin_amdgcn_mfma_f32_16x16x32_bf16(al1, PC2, acc0, 0, 0, 0);\
            acc1 = __builtin_amdgcn_mfma_f32_16x16x32_bf16(ah1, PC3, acc1, 0, 0, 0);\
            acc1 = __builtin_amdgcn_mfma_f32_16x16x32_bf16(ah1, PC7, acc1, 0, 0, 0);\
            acc1 = __builtin_amdgcn_mfma_f32_16x16x32_bf16(al1, PC3, acc1, 0, 0, 0);\
        }                                                                           \
        asm volatile("s_waitcnt lgkmcnt(0)" ::: "memory");  /* ds_writes done */    \
        __builtin_amdgcn_s_barrier();          /* single barrier: swap buffers */   \
    } while (0)

    for (int kt = 0; kt < NCH / 2; ++kt) {
        const int k0 = 2 * kt;
        CHUNK_BODY(k0,     1, 0, fxO0, fxO1, pA0, pA1, pA2, pA3, pA4, pA5, pA6, pA7,
                                             pB0, pB1, pB2, pB3, pB4, pB5, pB6, pB7);
        CHUNK_BODY(k0 + 1, 0, 1, fxE0, fxE1, pB0, pB1, pB2, pB3, pB4, pB5, pB6, pB7,
                                             pA0, pA1, pA2, pA3, pA4, pA5, pA6, pA7);
    }
#undef CHUNK_BODY

    // accumulators -> LDS logits tile. D layout: row = 4q+i (token), col = m (expert)
    {
        float* lr = lg + (16 * tg + 4 * q) * 68 + 32 * eh + m;
#pragma unroll
        for (int i = 0; i < 4; ++i) {
            lr[i * 68]      = acc0[i];
            lr[i * 68 + 16] = acc1[i];
        }
    }
    __syncthreads();

    // gating: 8 threads per token, thread jj owns experts 8jj..8jj+7
    const int tt = tid >> 3;
    const int jj = tid & 7;
    const float* row = lg + tt * 68 + jj * 8;
    const f32x4 lv0 = *reinterpret_cast<const f32x4*>(row);
    const f32x4 lv1 = *reinterpret_cast<const f32x4*>(row + 4);
    const float r[8] = {lv0[0], lv0[1], lv0[2], lv0[3], lv1[0], lv1[1], lv1[2], lv1[3]};

    // coalesced logits write
    float* gout = out + (size_t)(t0 + tt) * EE + jj * 8;
    *reinterpret_cast<f32x4*>(gout)     = lv0;
    *reinterpret_cast<f32x4*>(gout + 4) = lv1;

    // local top-2 (ascending expert order -> lowest index kept on ties)
    float v1 = -INFINITY, v2 = -INFINITY;
    int   i1 = 0, i2 = 0;
#pragma unroll
    for (int c = 0; c < 8; ++c) {
        const int e = jj * 8 + c;
        const float v = r[c];
        if (v > v1)      { v2 = v1; i2 = i1; v1 = v; i1 = e; }
        else if (v > v2) { v2 = v;  i2 = e; }
    }
    // butterfly merge across the 8-lane group (jax tie-break: lower index wins)
#pragma unroll
    for (int mk = 1; mk < 8; mk <<= 1) {
        const float ov1 = __shfl_xor(v1, mk);
        const int   oi1 = __shfl_xor(i1, mk);
        const float ov2 = __shfl_xor(v2, mk);
        const int   oi2 = __shfl_xor(i2, mk);
        const bool aw = (v1 > ov1) || (v1 == ov1 && i1 < oi1);
        const float c1v = aw ? v1 : ov1;  const int c1i = aw ? i1 : oi1;
        const float cav = aw ? v2 : ov2;  const int cai = aw ? i2 : oi2;
        const float cbv = aw ? ov1 : v1;  const int cbi = aw ? oi1 : i1;
        const bool bw = (cav > cbv) || (cav == cbv && cai < cbi);
        v1 = c1v; i1 = c1i;
        v2 = bw ? cav : cbv;
        i2 = bw ? cai : cbi;
    }

    // logsumexp over all 64 experts (v1 is the global max after the butterfly)
    float sm = 0.f;
#pragma unroll
    for (int c = 0; c < 8; ++c) sm += expf(r[c] - v1);
#pragma unroll
    for (int mk = 1; mk < 8; mk <<= 1) sm += __shfl_xor(sm, mk);

    const float logz = v1 + logf(sm);
    if (jj == 0) out[(size_t)2 * TTOK * EE + t0 + tt] = logz * logz;

    // 2-way softmax scores scattered into the 64-expert vector
    const float e21 = expf(v2 - v1);
    const float rr  = 1.f / (1.f + e21);
    const float sc1 = rr, sc2 = e21 * rr;
    float* sc = out + (size_t)TTOK * EE + (size_t)(t0 + tt) * EE + jj * 8;
    float vv[8];
#pragma unroll
    for (int c = 0; c < 8; ++c) {
        const int e = jj * 8 + c;
        vv[c] = (e == i1) ? sc1 : ((e == i2) ? sc2 : 0.f);
    }
    *reinterpret_cast<f32x4*>(sc)     = (f32x4){vv[0], vv[1], vv[2], vv[3]};
    *reinterpret_cast<f32x4*>(sc + 4) = (f32x4){vv[4], vv[5], vv[6], vv[7]};
}

extern "C" void kernel_launch(void* const* d_in, const int* in_sizes, int n_in,
                              void* d_out, int out_size, void* d_ws, size_t ws_size,
                              hipStream_t stream) {
    const float* x = (const float*)d_in[0];
    const float* W = (const float*)d_in[1];
    float* out = (float*)d_out;
    unsigned short* whi = (unsigned short*)d_ws;
    unsigned short* wlo = whi + (size_t)EE * DD;

    w_convert<<<dim3(EE * DD / 8 / 256), dim3(256), 0, stream>>>(W, whi, wlo);
    moe_fused<<<dim3(TTOK / TM), dim3(256), 0, stream>>>(x, whi, wlo, out);
}